// Round 14
// baseline (135.523 us; speedup 1.0000x reference)
//
#include <hip/hip_runtime.h>
#include <stdint.h>

#define B_DIM 4096
#define C_DIM 32
#define D_DIM 128
#define R_DIM 8
#define BM    64           // 4 independent waves x 16 rows
#define NTHREADS 256

typedef __bf16 bf16x8 __attribute__((ext_vector_type(8)));
typedef float  f32x4  __attribute__((ext_vector_type(4)));

// f32 -> bf16 bits, round-to-nearest-even
__device__ __forceinline__ uint32_t f2bf(float f) {
  uint32_t u = __float_as_uint(f);
  return (u + 0x7FFFu + ((u >> 16) & 1u)) >> 16;
}

#if __has_builtin(__builtin_amdgcn_exp2f)
#define EXP2F(x) __builtin_amdgcn_exp2f(x)
#else
#define EXP2F(x) exp2f(x)
#endif
#if __has_builtin(__builtin_amdgcn_rcpf)
#define RCPF(x) __builtin_amdgcn_rcpf(x)
#else
#define RCPF(x) (1.0f / (x))
#endif

// DPP row_ror add tree: 16-lane reduction entirely on the VALU pipe.
template <int CTRL>
__device__ __forceinline__ float ror_add(float v) {
  int r = __builtin_amdgcn_update_dpp(0, __builtin_bit_cast(int, v), CTRL, 0xf, 0xf, true);
  return v + __builtin_bit_cast(float, r);
}
__device__ __forceinline__ float red16(float v) {
  v = ror_add<0x128>(v);   // ROW_ROR:8
  v = ror_add<0x124>(v);   // ROW_ROR:4
  v = ror_add<0x122>(v);   // ROW_ROR:2
  v = ror_add<0x121>(v);   // ROW_ROR:1
  return v;
}

// ---- prep 1: W f32 -> bf16, [r][n][kt][lane][8 bf16]: the B-fragment for
// (n,kt) is a CONTIGUOUS 1KB block (lane*16 + imm) -> one global_load_dwordx4,
// perfectly coalesced, L1-line-aligned. W_r = 32KB = exactly one L1.
__global__ void prep_w(const float* __restrict__ W, uint32_t* __restrict__ ws) {
  uint32_t t = blockIdx.x * 256u + threadIdx.x;   // 65536 threads, one dword each
  uint32_t c  = t >> 2;
  uint32_t j  = t & 3u;
  uint32_t ln = c & 63u;
  uint32_t kt = (c >> 6) & 3u;
  uint32_t n  = (c >> 8) & 7u;
  uint32_t r  = c >> 11;
  uint32_t o  = n * 16u + (ln & 15u);
  uint32_t k  = kt * 32u + (ln >> 4) * 8u + j * 2u;
  const float2 w2 = *reinterpret_cast<const float2*>(
      W + ((size_t)(r * 128u + o)) * 128u + k);
  ws[t] = f2bf(w2.x) | (f2bf(w2.y) << 16);
}

// ---- prep 2: fold DynamicTanh params.
// wsA  [c][r][col] f32 = a*2log2(e)
// wsMC [c][r][col] u32 = bf16(c+d)<<16 | bf16(-2c)
__global__ void prep_acd(const float* __restrict__ A, const float* __restrict__ C,
                         const float* __restrict__ D, float* __restrict__ oA,
                         uint32_t* __restrict__ oMC) {
  uint32_t t = blockIdx.x * 256u + threadIdx.x;   // 32768 threads
  uint32_t col = t & 127u, r = (t >> 7) & 7u, c = t >> 10;
  uint32_t in = (r * 32u + c) * 128u + col;
  float av = A[in], cv = C[in], dv = D[in];
  uint32_t idx = (c * 8u + r) * 128u + col;
  oA[idx]  = av * 2.88539008177793f;
  oMC[idx] = (f2bf(cv + dv) << 16) | f2bf(-2.f * cv);
}

// Barrier-free, LDS-free: W_r B-fragments stream from L1/L2 straight into
// VGPRs (all 16 waves on a CU read the same 32KB -> L1 serves 15/16 of it,
// a pipe that was idle; the LDS port was the measured 72%-busy bottleneck).
// No __syncthreads anywhere; waves are fully independent.
__global__ __launch_bounds__(NTHREADS, 4)
void rot_kernel(const float* __restrict__ src, const float* __restrict__ data,
                const uint8_t* __restrict__ wsw, const float* __restrict__ wsA,
                const uint32_t* __restrict__ wsMC, float* __restrict__ out)
{
  const uint32_t tid  = threadIdx.x;
  const uint32_t lane = tid & 63u;
  const uint32_t wid  = tid >> 6;     // wave 0..3, fully independent
  const uint32_t l15  = lane & 15u;
  const uint32_t lg   = lane >> 4;

  const uint32_t c0   = blockIdx.x & 31u;
  const uint32_t rowb = (blockIdx.x >> 5) * BM + wid * 16u;

  // ---- x (data) in registers, MFMA C/D fragment layout ----
  f32x4 x[8];
  #pragma unroll
  for (int q = 0; q < 4; ++q) {
    const float* xr = data + ((size_t)(rowb + lg * 4 + q) * C_DIM + c0) * D_DIM;
    #pragma unroll
    for (int n = 0; n < 8; ++n) x[n][q] = xr[n * 16 + l15];
  }

  // ---- source A-fragments (bf16, converted once) ----
  bf16x8 af[4];
  {
    const float* sr = src + ((size_t)(rowb + l15) * C_DIM + c0) * D_DIM + lg * 8u;
    #pragma unroll
    for (int kt = 0; kt < 4; ++kt) {
      float4 f0 = *reinterpret_cast<const float4*>(sr + kt * 32);
      float4 f1 = *reinterpret_cast<const float4*>(sr + kt * 32 + 4);
      union { uint32_t u[4]; bf16x8 v; } p;
      p.u[0] = f2bf(f0.x) | (f2bf(f0.y) << 16);
      p.u[1] = f2bf(f0.z) | (f2bf(f0.w) << 16);
      p.u[2] = f2bf(f1.x) | (f2bf(f1.y) << 16);
      p.u[3] = f2bf(f1.z) | (f2bf(f1.w) << 16);
      af[kt] = p.v;
    }
  }

  for (int r = 0; r < R_DIM; ++r) {
    // ---- V = S @ W_r^T: bq fragments from L1/L2 (frag-ordered ws) ----
    const bf16x8* wb = reinterpret_cast<const bf16x8*>(
        wsw + (uint32_t)r * 32768u + lane * 16u);   // elem stride = 16 B
    f32x4 acc[8];
    #pragma unroll
    for (int n = 0; n < 8; ++n) acc[n] = (f32x4){0.f, 0.f, 0.f, 0.f};
    #pragma unroll
    for (int kt = 0; kt < 4; ++kt) {
      bf16x8 bq[8];
      #pragma unroll
      for (int n = 0; n < 8; ++n)
        bq[n] = wb[(uint32_t)(n * 4 + kt) * 64u];   // contiguous 1KB per load
      #pragma unroll
      for (int n = 0; n < 8; ++n)
        acc[n] = __builtin_amdgcn_mfma_f32_16x16x32_bf16(af[kt], bq[n], acc[n], 0, 0, 0);
    }

    // ---- epilogue: t = tanh(a*v)*c + d;  x -= 2*t*(t.x)/max(||t||,eps)^2 ----
    // acd from global (4KB tables, L1-hot); loads are acc-independent so the
    // compiler batches them ahead of the trans chains.
    const float*    pA = wsA  + (uint32_t)(c0 * 8 + r) * 128u;
    const uint32_t* pM = wsMC + (uint32_t)(c0 * 8 + r) * 128u;
    f32x4 s2 = {0.f,0.f,0.f,0.f}, tx = {0.f,0.f,0.f,0.f};
    #pragma unroll
    for (int n = 0; n < 8; ++n) {
      float    a2  = pA[n * 16 + l15];
      uint32_t mcu = pM[n * 16 + l15];
      float m2c = __builtin_bit_cast(float, mcu << 16);          // bf16 -> f32
      float cdv = __builtin_bit_cast(float, mcu & 0xffff0000u);  // bf16 -> f32
      f32x4 z = acc[n] * a2;
      f32x4 ep;
      #pragma unroll
      for (int q = 0; q < 4; ++q) ep[q] = EXP2F(z[q]);
      ep = ep + 1.0f;
      f32x4 pr;
      #pragma unroll
      for (int q = 0; q < 4; ++q) pr[q] = RCPF(ep[q]);
      f32x4 t = pr * m2c + cdv;
      acc[n] = t;
      s2 = s2 + t * t;
      tx = tx + t * x[n];
    }
    f32x4 sc;
    #pragma unroll
    for (int q = 0; q < 4; ++q) {
      float s = red16(s2[q]);
      float d = red16(tx[q]);
      sc[q] = -2.f * d * RCPF(fmaxf(s, 1e-24f));
    }
    #pragma unroll
    for (int n = 0; n < 8; ++n)
      x[n] = x[n] + sc * acc[n];
  }

  // ---- store ----
  #pragma unroll
  for (int q = 0; q < 4; ++q) {
    float* orow = out + ((size_t)(rowb + lg * 4 + q) * C_DIM + c0) * D_DIM;
    #pragma unroll
    for (int n = 0; n < 8; ++n) orow[n * 16 + l15] = x[n][q];
  }
}

extern "C" void kernel_launch(void* const* d_in, const int* in_sizes, int n_in,
                              void* d_out, int out_size, void* d_ws, size_t ws_size,
                              hipStream_t stream) {
  const float* src  = (const float*)d_in[0];
  const float* data = (const float*)d_in[1];
  const float* W    = (const float*)d_in[2];
  const float* Aa   = (const float*)d_in[3];
  const float* Cc   = (const float*)d_in[4];
  const float* Dd   = (const float*)d_in[5];
  float* out = (float*)d_out;

  uint8_t* wsW  = (uint8_t*)d_ws;              // 256 KB bf16 W, frag-ordered
  uint8_t* wsA  = wsW + 262144;                // 128 KB a2 table (f32)
  uint8_t* wsMC = wsA + 131072;                // 128 KB packed bf16 {cdv|m2c}

  prep_w<<<dim3(256), dim3(256), 0, stream>>>(W, (uint32_t*)wsW);
  prep_acd<<<dim3(128), dim3(256), 0, stream>>>(Aa, Cc, Dd, (float*)wsA, (uint32_t*)wsMC);

  dim3 grid((B_DIM / BM) * C_DIM);   // 2048 workgroups of 256 (4 free waves)
  dim3 block(NTHREADS);
  rot_kernel<<<grid, block, 0, stream>>>(src, data, wsW, (const float*)wsA,
                                         (const uint32_t*)wsMC, out);
}

// Round 15
// 110.550 us; speedup vs baseline: 1.2259x; 1.2259x over previous
//
#include <hip/hip_runtime.h>
#include <stdint.h>

#define B_DIM 4096
#define C_DIM 32
#define D_DIM 128
#define R_DIM 8
#define BM    64           // 4 waves x 16 rows
#define NTHREADS 256

typedef __bf16 bf16x8 __attribute__((ext_vector_type(8)));
typedef float  f32x4  __attribute__((ext_vector_type(4)));

// f32 -> bf16 bits, round-to-nearest-even
__device__ __forceinline__ uint32_t f2bf(float f) {
  uint32_t u = __float_as_uint(f);
  return (u + 0x7FFFu + ((u >> 16) & 1u)) >> 16;
}

#if __has_builtin(__builtin_amdgcn_exp2f)
#define EXP2F(x) __builtin_amdgcn_exp2f(x)
#else
#define EXP2F(x) exp2f(x)
#endif
#if __has_builtin(__builtin_amdgcn_rcpf)
#define RCPF(x) __builtin_amdgcn_rcpf(x)
#else
#define RCPF(x) (1.0f / (x))
#endif

// 16B async global->LDS. LDS dest wave-uniform + lane*16; global addr per-lane.
__device__ __forceinline__ void load_lds16(const void* g, void* l) {
  __builtin_amdgcn_global_load_lds(
      (const __attribute__((address_space(1))) uint32_t*)g,
      (__attribute__((address_space(3))) uint32_t*)l, 16, 0, 0);
}

// DPP row_ror add tree: 16-lane reduction entirely on the VALU pipe.
template <int CTRL>
__device__ __forceinline__ float ror_add(float v) {
  int r = __builtin_amdgcn_update_dpp(0, __builtin_bit_cast(int, v), CTRL, 0xf, 0xf, true);
  return v + __builtin_bit_cast(float, r);
}
__device__ __forceinline__ float red16(float v) {
  v = ror_add<0x128>(v);   // ROW_ROR:8
  v = ror_add<0x124>(v);   // ROW_ROR:4
  v = ror_add<0x122>(v);   // ROW_ROR:2
  v = ror_add<0x121>(v);   // ROW_ROR:1
  return v;
}

// ---- prep 1: W f32 -> bf16, [r][n][kt][lane][8 bf16]: B-frag (n,kt) is a
// CONTIGUOUS 1KB block (lane*16 + imm). n=0..3 half -> LDS; n=4..7 -> L1.
__global__ void prep_w(const float* __restrict__ W, uint32_t* __restrict__ ws) {
  uint32_t t = blockIdx.x * 256u + threadIdx.x;   // 65536 threads, one dword each
  uint32_t c  = t >> 2;
  uint32_t j  = t & 3u;
  uint32_t ln = c & 63u;
  uint32_t kt = (c >> 6) & 3u;
  uint32_t n  = (c >> 8) & 7u;
  uint32_t r  = c >> 11;
  uint32_t o  = n * 16u + (ln & 15u);
  uint32_t k  = kt * 32u + (ln >> 4) * 8u + j * 2u;
  const float2 w2 = *reinterpret_cast<const float2*>(
      W + ((size_t)(r * 128u + o)) * 128u + k);
  ws[t] = f2bf(w2.x) | (f2bf(w2.y) << 16);
}

// ---- prep 2: fold DynamicTanh params.
// wsA  [c][r][col] f32 = a*2log2(e)
// wsMC [c][r][col] u32 = bf16(c+d)<<16 | bf16(-2c)
__global__ void prep_acd(const float* __restrict__ A, const float* __restrict__ C,
                         const float* __restrict__ D, float* __restrict__ oA,
                         uint32_t* __restrict__ oMC) {
  uint32_t t = blockIdx.x * 256u + threadIdx.x;   // 32768 threads
  uint32_t col = t & 127u, r = (t >> 7) & 7u, c = t >> 10;
  uint32_t in = (r * 32u + c) * 128u + col;
  float av = A[in], cv = C[in], dv = D[in];
  uint32_t idx = (c * 8u + r) * 128u + col;
  oA[idx]  = av * 2.88539008177793f;
  oMC[idx] = (f2bf(cv + dv) << 16) | f2bf(-2.f * cv);
}

// stage the 16KB LDS-half (n=0..3) of W_{r1} into buffer bsel
__device__ __forceinline__ void stage_half(const uint8_t* __restrict__ wsw,
                                           unsigned char* ldsW, uint32_t r1,
                                           uint32_t bsel, uint32_t wid, uint32_t lane) {
  const uint8_t* g = wsw + r1 * 32768u;
  unsigned char* d = ldsW + bsel * 16384u;
  #pragma unroll
  for (int j = 0; j < 4; ++j)
    load_lds16(g + wid * 1024u + (uint32_t)j * 4096u + lane * 16u,
               d + wid * 1024u + (uint32_t)j * 4096u);
}

// Hybrid-port kernel: B-fragments n=0..3 from LDS (double-buffered 16KB
// halves, one barrier/r), n=4..7 streamed from L1 (same 16KB for all 16
// waves/CU -> L1-resident). LDS port time halves; L1/TA path was idle.
__global__ __launch_bounds__(NTHREADS, 4)
void rot_kernel(const float* __restrict__ src, const float* __restrict__ data,
                const uint8_t* __restrict__ wsw, const float* __restrict__ wsA,
                const uint32_t* __restrict__ wsMC, float* __restrict__ out)
{
  __shared__ __align__(16) unsigned char ldsW[2 * 16384];  // dbuf'd n=0..3 half

  const uint32_t tid  = threadIdx.x;
  const uint32_t lane = tid & 63u;
  const uint32_t wid  = tid >> 6;     // wave 0..3, owns 16 rows
  const uint32_t l15  = lane & 15u;
  const uint32_t lg   = lane >> 4;

  const uint32_t c0   = blockIdx.x & 31u;
  const uint32_t rowb = (blockIdx.x >> 5) * BM + wid * 16u;

  // ---- prologue: stage W_0's LDS-half into buf0 ----
  stage_half(wsw, ldsW, 0, 0, wid, lane);

  // ---- x (data) in registers, MFMA C/D fragment layout ----
  f32x4 x[8];
  #pragma unroll
  for (int q = 0; q < 4; ++q) {
    const float* xr = data + ((size_t)(rowb + lg * 4 + q) * C_DIM + c0) * D_DIM;
    #pragma unroll
    for (int n = 0; n < 8; ++n) x[n][q] = xr[n * 16 + l15];
  }

  // ---- source A-fragments (bf16, converted once) ----
  bf16x8 af[4];
  {
    const float* sr = src + ((size_t)(rowb + l15) * C_DIM + c0) * D_DIM + lg * 8u;
    #pragma unroll
    for (int kt = 0; kt < 4; ++kt) {
      float4 f0 = *reinterpret_cast<const float4*>(sr + kt * 32);
      float4 f1 = *reinterpret_cast<const float4*>(sr + kt * 32 + 4);
      union { uint32_t u[4]; bf16x8 v; } p;
      p.u[0] = f2bf(f0.x) | (f2bf(f0.y) << 16);
      p.u[1] = f2bf(f0.z) | (f2bf(f0.w) << 16);
      p.u[2] = f2bf(f1.x) | (f2bf(f1.y) << 16);
      p.u[3] = f2bf(f1.z) | (f2bf(f1.w) << 16);
      af[kt] = p.v;
    }
  }

  __syncthreads();   // vmcnt(0) drain: W_0 half in LDS

  for (int r = 0; r < R_DIM; ++r) {
    // ---- issue stage of W_{r+1}'s LDS-half into the other buffer; it
    // drains under this whole iteration, enforced by the end barrier ----
    if (r < 7) stage_half(wsw, ldsW, r + 1, (r + 1) & 1, wid, lane);

    // ---- V = S @ W_r^T: n=0..3 from LDS buf, n=4..7 from L1 ----
    const unsigned char* lb = ldsW + (uint32_t)((r & 1) * 16384) + lane * 16u;
    const uint8_t*       gb = wsw + (uint32_t)r * 32768u + 16384u + lane * 16u;
    f32x4 acc[8];
    #pragma unroll
    for (int n = 0; n < 8; ++n) acc[n] = (f32x4){0.f, 0.f, 0.f, 0.f};
    #pragma unroll
    for (int kt = 0; kt < 4; ++kt) {
      bf16x8 bg[4];   // global half first: long-latency loads issue early
      #pragma unroll
      for (int i = 0; i < 4; ++i)
        bg[i] = *reinterpret_cast<const bf16x8*>(gb + (uint32_t)((i * 4 + kt) * 1024));
      bf16x8 bl[4];
      #pragma unroll
      for (int i = 0; i < 4; ++i)
        bl[i] = *reinterpret_cast<const bf16x8*>(lb + (uint32_t)((i * 4 + kt) * 1024));
      #pragma unroll
      for (int i = 0; i < 4; ++i)
        acc[i]     = __builtin_amdgcn_mfma_f32_16x16x32_bf16(af[kt], bl[i], acc[i], 0, 0, 0);
      #pragma unroll
      for (int i = 0; i < 4; ++i)
        acc[4 + i] = __builtin_amdgcn_mfma_f32_16x16x32_bf16(af[kt], bg[i], acc[4 + i], 0, 0, 0);
    }

    // ---- epilogue: t = tanh(a*v)*c + d;  x -= 2*t*(t.x)/max(||t||,eps)^2 ----
    // acd from global (4KB/c0 tables, L1-hot; keeps the LDS port clear)
    const float*    pA = wsA  + (uint32_t)(c0 * 8 + r) * 128u;
    const uint32_t* pM = wsMC + (uint32_t)(c0 * 8 + r) * 128u;
    f32x4 s2 = {0.f,0.f,0.f,0.f}, tx = {0.f,0.f,0.f,0.f};
    #pragma unroll
    for (int n = 0; n < 8; ++n) {
      float    a2  = pA[n * 16 + l15];
      uint32_t mcu = pM[n * 16 + l15];
      float m2c = __builtin_bit_cast(float, mcu << 16);          // bf16 -> f32
      float cdv = __builtin_bit_cast(float, mcu & 0xffff0000u);  // bf16 -> f32
      f32x4 z = acc[n] * a2;
      f32x4 ep;
      #pragma unroll
      for (int q = 0; q < 4; ++q) ep[q] = EXP2F(z[q]);
      ep = ep + 1.0f;
      f32x4 pr;
      #pragma unroll
      for (int q = 0; q < 4; ++q) pr[q] = RCPF(ep[q]);
      f32x4 t = pr * m2c + cdv;
      acc[n] = t;
      s2 = s2 + t * t;
      tx = tx + t * x[n];
    }
    f32x4 sc;
    #pragma unroll
    for (int q = 0; q < 4; ++q) {
      float s = red16(s2[q]);
      float d = red16(tx[q]);
      sc[q] = -2.f * d * RCPF(fmaxf(s, 1e-24f));
    }
    #pragma unroll
    for (int n = 0; n < 8; ++n)
      x[n] = x[n] + sc * acc[n];

    __syncthreads();   // single barrier/r: drains stage (vmcnt0) + fences
                       // buf[(r+1)&1] reads before it is restaged in r+1
  }

  // ---- store ----
  #pragma unroll
  for (int q = 0; q < 4; ++q) {
    float* orow = out + ((size_t)(rowb + lg * 4 + q) * C_DIM + c0) * D_DIM;
    #pragma unroll
    for (int n = 0; n < 8; ++n) orow[n * 16 + l15] = x[n][q];
  }
}

extern "C" void kernel_launch(void* const* d_in, const int* in_sizes, int n_in,
                              void* d_out, int out_size, void* d_ws, size_t ws_size,
                              hipStream_t stream) {
  const float* src  = (const float*)d_in[0];
  const float* data = (const float*)d_in[1];
  const float* W    = (const float*)d_in[2];
  const float* Aa   = (const float*)d_in[3];
  const float* Cc   = (const float*)d_in[4];
  const float* Dd   = (const float*)d_in[5];
  float* out = (float*)d_out;

  uint8_t* wsW  = (uint8_t*)d_ws;              // 256 KB bf16 W, frag-ordered
  uint8_t* wsA  = wsW + 262144;                // 128 KB a2 table (f32)
  uint8_t* wsMC = wsA + 131072;                // 128 KB packed bf16 {cdv|m2c}

  prep_w<<<dim3(256), dim3(256), 0, stream>>>(W, (uint32_t*)wsW);
  prep_acd<<<dim3(128), dim3(256), 0, stream>>>(Aa, Cc, Dd, (float*)wsA, (uint32_t*)wsMC);

  dim3 grid((B_DIM / BM) * C_DIM);   // 2048 workgroups of 256
  dim3 block(NTHREADS);
  rot_kernel<<<grid, block, 0, stream>>>(src, data, wsW, (const float*)wsA,
                                         (const uint32_t*)wsMC, out);
}